// Round 2
// baseline (6221.786 us; speedup 1.0000x reference)
//
#include <hip/hip_runtime.h>

#define BT 2
#define LSEQ 1024
#define TT 2048      // total tokens
#define DM 768
#define DI 1536
#define DI2 3072
#define DS 16
#define DR 48
#define NL 4
#define VOC 32000
#define EPSV 1e-5f

typedef __attribute__((ext_vector_type(8))) short short8;
typedef __attribute__((ext_vector_type(4))) float f32x4;

__device__ __forceinline__ short f2b(float f) {
  unsigned u = __float_as_uint(f);
  unsigned r = (u + 0x7FFFu + ((u >> 16) & 1u)) >> 16;   // round-to-nearest-even
  return (short)r;
}
__device__ __forceinline__ float b2f(short s) {
  return __uint_as_float(((unsigned)(unsigned short)s) << 16);
}

// split 8 consecutive fp32 into hi/lo bf16 fragments (x ~= hi + lo, err ~2^-17)
__device__ __forceinline__ void split8(const float* __restrict__ p, short8& hi, short8& lo) {
  f32x4 v0 = *(const f32x4*)p;
  f32x4 v1 = *(const f32x4*)(p + 4);
  float f[8] = {v0[0], v0[1], v0[2], v0[3], v1[0], v1[1], v1[2], v1[3]};
#pragma unroll
  for (int j = 0; j < 8; j++) {
    short h = f2b(f[j]);
    hi[j] = h;
    lo[j] = f2b(f[j] - b2f(h));
  }
}

// ---------------- embedding gather -> fp32 residual stream ----------------
__global__ void k_embed(const int* __restrict__ ids, const float* __restrict__ emb,
                        float* __restrict__ x) {
  int idx = blockIdx.x * 256 + threadIdx.x;
  int t = idx / DM, c = idx % DM;
  x[idx] = emb[(size_t)ids[t] * DM + c];
}

// ---------------- rmsnorm (fp32 -> fp32) ----------------
__global__ void k_rmsnorm(const float* __restrict__ x, const float* __restrict__ w,
                          float* __restrict__ out) {
  int t = blockIdx.x;
  const float* xrow = x + (size_t)t * DM;
  float v[3];
  float p = 0.f;
#pragma unroll
  for (int k = 0; k < 3; k++) {
    v[k] = xrow[threadIdx.x + k * 256];
    p += v[k] * v[k];
  }
  for (int o = 32; o; o >>= 1) p += __shfl_down(p, o, 64);
  __shared__ float sred[4];
  int wave = threadIdx.x >> 6, lane = threadIdx.x & 63;
  if (lane == 0) sred[wave] = p;
  __syncthreads();
  float ss = sred[0] + sred[1] + sred[2] + sred[3];
  float sc = rsqrtf(ss / (float)DM + EPSV);
  float* orow = out + (size_t)t * DM;
#pragma unroll
  for (int k = 0; k < 3; k++) {
    int c = threadIdx.x + k * 256;
    orow[c] = v[k] * sc * w[c];
  }
}

// ------- GEMM: C[M,N] = A[M,K] * W[N,K]^T, fp32 in/out via split-bf16 -------
// 3 MFMAs per tile: ah*bh + ah*bl + al*bh  (drops lo*lo ~ 2^-32)
// MODE 0: store    MODE 1: += (residual)
template <int MODE>
__global__ void __launch_bounds__(256)
k_gemm(const float* __restrict__ A, const float* __restrict__ W,
       float* __restrict__ C, int N, int K) {
  int lane = threadIdx.x & 63;
  int wave = threadIdx.x >> 6;
  int quad = lane >> 4;
  int l16 = lane & 15;
  int bm = blockIdx.x * 64 + (wave >> 1) * 32;
  int bn = blockIdx.y * 64 + (wave & 1) * 32;
  f32x4 acc[2][2] = {{{0.f,0.f,0.f,0.f},{0.f,0.f,0.f,0.f}},
                     {{0.f,0.f,0.f,0.f},{0.f,0.f,0.f,0.f}}};
  const float* a0 = A + (size_t)(bm + l16) * K + quad * 8;
  const float* a1 = a0 + (size_t)16 * K;
  const float* b0 = W + (size_t)(bn + l16) * K + quad * 8;
  const float* b1 = b0 + (size_t)16 * K;
  for (int k0 = 0; k0 < K; k0 += 32) {
    short8 ah0, al0, ah1, al1, bh0, bl0, bh1, bl1;
    split8(a0 + k0, ah0, al0);
    split8(a1 + k0, ah1, al1);
    split8(b0 + k0, bh0, bl0);
    split8(b1 + k0, bh1, bl1);
    acc[0][0] = __builtin_amdgcn_mfma_f32_16x16x32_bf16(ah0, bh0, acc[0][0], 0, 0, 0);
    acc[0][1] = __builtin_amdgcn_mfma_f32_16x16x32_bf16(ah0, bh1, acc[0][1], 0, 0, 0);
    acc[1][0] = __builtin_amdgcn_mfma_f32_16x16x32_bf16(ah1, bh0, acc[1][0], 0, 0, 0);
    acc[1][1] = __builtin_amdgcn_mfma_f32_16x16x32_bf16(ah1, bh1, acc[1][1], 0, 0, 0);
    acc[0][0] = __builtin_amdgcn_mfma_f32_16x16x32_bf16(ah0, bl0, acc[0][0], 0, 0, 0);
    acc[0][1] = __builtin_amdgcn_mfma_f32_16x16x32_bf16(ah0, bl1, acc[0][1], 0, 0, 0);
    acc[1][0] = __builtin_amdgcn_mfma_f32_16x16x32_bf16(ah1, bl0, acc[1][0], 0, 0, 0);
    acc[1][1] = __builtin_amdgcn_mfma_f32_16x16x32_bf16(ah1, bl1, acc[1][1], 0, 0, 0);
    acc[0][0] = __builtin_amdgcn_mfma_f32_16x16x32_bf16(al0, bh0, acc[0][0], 0, 0, 0);
    acc[0][1] = __builtin_amdgcn_mfma_f32_16x16x32_bf16(al0, bh1, acc[0][1], 0, 0, 0);
    acc[1][0] = __builtin_amdgcn_mfma_f32_16x16x32_bf16(al1, bh0, acc[1][0], 0, 0, 0);
    acc[1][1] = __builtin_amdgcn_mfma_f32_16x16x32_bf16(al1, bh1, acc[1][1], 0, 0, 0);
  }
#pragma unroll
  for (int i = 0; i < 2; i++)
#pragma unroll
    for (int j = 0; j < 2; j++) {
      int m0 = bm + i * 16 + quad * 4;
      int n = bn + j * 16 + l16;
#pragma unroll
      for (int r = 0; r < 4; r++) {
        size_t off = (size_t)(m0 + r) * N + n;
        float v = acc[i][j][r];
        if (MODE == 0) C[off] = v;
        else C[off] += v;
      }
    }
}

// ---------------- causal depthwise conv1d + bias + silu ----------------
__global__ void k_conv_silu(const float* __restrict__ xr, const float* __restrict__ cw,
                            const float* __restrict__ cb, float* __restrict__ u) {
  int idx = blockIdx.x * 256 + threadIdx.x;
  int t = idx / DI, d = idx % DI;
  int l = t & (LSEQ - 1);
  float acc = cb[d];
#pragma unroll
  for (int j = 0; j < 4; j++) {
    int ll = l - 3 + j;
    if (ll >= 0) acc += xr[(size_t)(t - 3 + j) * DI2 + d] * cw[d * 4 + j];
  }
  u[idx] = acc / (1.f + __expf(-acc));
}

// ---------------- x_proj: (1536) -> (80) per token ----------------
__global__ void __launch_bounds__(128)
k_xproj(const float* __restrict__ u, const float* __restrict__ w, float* __restrict__ xdbl) {
  __shared__ float su[DI];
  int t = blockIdx.x;
  for (int k = threadIdx.x; k < DI; k += 128) su[k] = u[(size_t)t * DI + k];
  __syncthreads();
  int o = threadIdx.x;
  if (o < 80) {
    const float* wr = w + (size_t)o * DI;
    float acc = 0.f;
    for (int k = 0; k < DI; k += 4) {
      f32x4 wv = *(const f32x4*)(wr + k);
      acc += su[k] * wv[0] + su[k + 1] * wv[1] + su[k + 2] * wv[2] + su[k + 3] * wv[3];
    }
    xdbl[(size_t)t * 80 + o] = acc;
  }
}

// ---------------- dt_proj (48 -> 1536) + softplus ----------------
__global__ void __launch_bounds__(256)
k_dtproj(const float* __restrict__ xdbl, const float* __restrict__ w,
         const float* __restrict__ bias, float* __restrict__ delta) {
  __shared__ float sd[DR];
  int t = blockIdx.y;
  int d = blockIdx.x * 256 + threadIdx.x;
  if (threadIdx.x < DR) sd[threadIdx.x] = xdbl[(size_t)t * 80 + threadIdx.x];
  __syncthreads();
  const float* wr = w + (size_t)d * DR;
  float acc = bias[d];
#pragma unroll
  for (int k = 0; k < DR; k += 4) {
    f32x4 wv = *(const f32x4*)(wr + k);
    acc += sd[k] * wv[0] + sd[k + 1] * wv[1] + sd[k + 2] * wv[2] + sd[k + 3] * wv[3];
  }
  float sp = (acc > 20.f) ? acc : log1pf(__expf(acc));
  delta[(size_t)t * DI + d] = sp;
}

// ---------------- selective scan: 16 lanes per channel (one per state) ----
// fused epilogue: y = (scan + D*u) * silu(res), fp32 out for out_proj
__global__ void __launch_bounds__(256)
k_scan(const float* __restrict__ delta, const float* __restrict__ u,
       const float* __restrict__ xdbl, const float* __restrict__ xr,
       const float* __restrict__ A_log, const float* __restrict__ Dp,
       float* __restrict__ y) {
  int tid = threadIdx.x;
  int n = tid & 15;
  int ch = blockIdx.x * 16 + (tid >> 4);
  int b = ch / DI, d = ch % DI;
  float An = -__expf(A_log[d * DS + n]);
  float Dd = Dp[d];
  const float* dp = delta + (size_t)b * LSEQ * DI + d;
  const float* up = u + (size_t)b * LSEQ * DI + d;
  const float* xd = xdbl + (size_t)b * LSEQ * 80;
  const float* rp = xr + (size_t)b * LSEQ * DI2 + DI + d;
  float* yp = y + (size_t)b * LSEQ * DI + d;
  float h = 0.f;
  for (int l = 0; l < LSEQ; l++) {
    float dt = dp[(size_t)l * DI];
    float uu = up[(size_t)l * DI];
    float Bn = xd[l * 80 + DR + n];
    float Cn = xd[l * 80 + DR + DS + n];
    float dA = __expf(dt * An);
    h = fmaf(dA, h, dt * Bn * uu);
    float p = h * Cn;
    p += __shfl_xor(p, 1, 16);
    p += __shfl_xor(p, 2, 16);
    p += __shfl_xor(p, 4, 16);
    p += __shfl_xor(p, 8, 16);
    if (n == 0) {
      float res = rp[(size_t)l * DI2];
      float yv = fmaf(Dd, uu, p);
      yp[(size_t)l * DI] = yv * (res / (1.f + __expf(-res)));
    }
  }
}

extern "C" void kernel_launch(void* const* d_in, const int* in_sizes, int n_in,
                              void* d_out, int out_size, void* d_ws, size_t ws_size,
                              hipStream_t stream) {
  const int* ids = (const int*)d_in[0];
  const float* emb = (const float*)d_in[4];
  const float* norm_w = (const float*)d_in[5];
  const float* in_proj_w = (const float*)d_in[6];
  const float* conv_w = (const float*)d_in[7];
  const float* conv_b = (const float*)d_in[8];
  const float* x_proj_w = (const float*)d_in[9];
  const float* dt_proj_w = (const float*)d_in[10];
  const float* dt_proj_b = (const float*)d_in[11];
  const float* A_log = (const float*)d_in[12];
  const float* D_param = (const float*)d_in[13];
  const float* out_proj_w = (const float*)d_in[14];
  const float* norm_f_w = (const float*)d_in[15];

  char* wp = (char*)d_ws;
  float* x = (float*)wp;    wp += (size_t)TT * DM * 4;
  float* xr = (float*)wp;   wp += (size_t)TT * DI2 * 4;
  float* u = (float*)wp;    wp += (size_t)TT * DI * 4;
  float* dl = (float*)wp;   wp += (size_t)TT * DI * 4;
  float* xdbl = (float*)wp; wp += (size_t)TT * 80 * 4;
  float* xn = (float*)wp;   wp += (size_t)TT * DM * 4;
  float* y = (float*)wp;    wp += (size_t)TT * DI * 4;

  k_embed<<<TT * DM / 256, 256, 0, stream>>>(ids, emb, x);
  for (int i = 0; i < NL; i++) {
    k_rmsnorm<<<TT, 256, 0, stream>>>(x, norm_w + (size_t)i * DM, xn);
    k_gemm<0><<<dim3(TT / 64, DI2 / 64), 256, 0, stream>>>(
        xn, in_proj_w + (size_t)i * DI2 * DM, xr, DI2, DM);
    k_conv_silu<<<TT * DI / 256, 256, 0, stream>>>(
        xr, conv_w + (size_t)i * DI * 4, conv_b + (size_t)i * DI, u);
    k_xproj<<<TT, 128, 0, stream>>>(u, x_proj_w + (size_t)i * 80 * DI, xdbl);
    k_dtproj<<<dim3(DI / 256, TT), 256, 0, stream>>>(
        xdbl, dt_proj_w + (size_t)i * DI * DR, dt_proj_b + (size_t)i * DI, dl);
    k_scan<<<BT * DI / 16, 256, 0, stream>>>(
        dl, u, xdbl, xr, A_log + (size_t)i * DI * DS, D_param + (size_t)i * DI, y);
    k_gemm<1><<<dim3(TT / 64, DM / 64), 256, 0, stream>>>(
        y, out_proj_w + (size_t)i * DM * DI, x, DM, DI);
  }
  k_rmsnorm<<<TT, 256, 0, stream>>>(x, norm_f_w, xn);
  k_gemm<0><<<dim3(TT / 64, VOC / 64), 256, 0, stream>>>(
      xn, emb, (float*)d_out, VOC, DM);
}